// Round 5
// baseline (9889.323 us; speedup 1.0000x reference)
//
#include <hip/hip_runtime.h>
#include <cstdint>
#include <cstddef>

// ---------------- problem constants ----------------
#define B_   64
#define P_   196
#define E_   2048
#define A_   512
#define D_   512
#define EMB_ 512
#define V_   10000
#define T_   40
// concatenated h-GEMM column space (loop): [dec_att(512) | f_beta(2048) | W_hh(2048)]
#define NCAT  4608
// fc weight transposed, N padded to multiple of 128
#define VPAD  10112
#define NBLK  256   // persistent grid = CU count

typedef unsigned short u16;
typedef __attribute__((ext_vector_type(8))) short bf16x8;  // 8 bf16 = 4 VGPRs
typedef __attribute__((ext_vector_type(4))) float f32x4;

__device__ __forceinline__ f32x4 mfma_bf16(bf16x8 a, bf16x8 b, f32x4 c) {
  return __builtin_amdgcn_mfma_f32_16x16x32_bf16(a, b, c, 0, 0, 0);
}
__device__ __forceinline__ u16 f2b(float f) {            // RNE f32->bf16 (no NaN in data)
  unsigned u = __builtin_bit_cast(unsigned, f);
  u += 0x7fffu + ((u >> 16) & 1u);
  return (u16)(u >> 16);
}
__device__ __forceinline__ float b2f(u16 s) {
  unsigned u = ((unsigned)s) << 16;
  return __builtin_bit_cast(float, u);
}
__device__ __forceinline__ float sigf(float x) { return 1.0f / (1.0f + __expf(-x)); }

// async global->LDS, 16B per lane. LDS dst must be wave-uniform; lane l lands at dst + l*16B.
__device__ __forceinline__ void gl_lds16(const u16* gsrc, u16* ldst) {
  __builtin_amdgcn_global_load_lds(
      (const __attribute__((address_space(1))) unsigned int*)gsrc,
      (__attribute__((address_space(3))) unsigned int*)ldst,
      16, 0, 0);
}

// software grid barrier: monotonic counter, agent-scope atomics + fences.
// All NBLK blocks must be co-resident (grid == CU count, 1 block/CU capacity).
__device__ __forceinline__ void gbar(unsigned* bar, unsigned target) {
  __syncthreads();
  if (threadIdx.x == 0) {
    __threadfence();   // publish this block's writes (L2 writeback on gfx950)
    __hip_atomic_fetch_add(bar, 1u, __ATOMIC_RELEASE, __HIP_MEMORY_SCOPE_AGENT);
    long spins = 0;
    while (__hip_atomic_load(bar, __ATOMIC_ACQUIRE, __HIP_MEMORY_SCOPE_AGENT) < target) {
      __builtin_amdgcn_s_sleep(8);
      if (++spins > (1L << 19)) break;  // ~0.1s bailout: fail visibly, don't hang
    }
    __threadfence();   // invalidate stale lines before next phase reads
  }
  __syncthreads();
}

// ---------------- prolog kernels ----------------
__global__ __launch_bounds__(256) void k_cvt_bf16(const float* __restrict__ s,
                                                  u16* __restrict__ d, int n4) {
  int i = blockIdx.x * 256 + threadIdx.x;
  if (i >= n4) return;
  float4 v = reinterpret_cast<const float4*>(s)[i];
  u16* o = d + (size_t)i * 4;
  o[0] = f2b(v.x); o[1] = f2b(v.y); o[2] = f2b(v.z); o[3] = f2b(v.w);
}

__global__ __launch_bounds__(256) void k_mean(const float* __restrict__ enc,
                                              u16* __restrict__ meanE_bf) {
  int i = blockIdx.x * 256 + threadIdx.x;   // 64*2048
  int b = i >> 11, e = i & 2047;
  const float* p = enc + (size_t)b * P_ * E_ + e;
  float s = 0.f;
  for (int pp = 0; pp < P_; ++pp) s += p[(size_t)pp * E_];
  meanE_bf[i] = f2b(s * (1.0f / (float)P_));
}

// dst[n*dstStride + k] = src[k*srcStride + n]  (fp32 -> bf16), LDS-tiled
__global__ __launch_bounds__(256) void k_transpose_bf16(
    const float* __restrict__ src, int srcStride,
    u16* __restrict__ dst, int dstStride, int N, int K) {
  __shared__ float t[32][33];
  int kt = blockIdx.x * 32, nt = blockIdx.y * 32;
  int tx = threadIdx.x & 31, ty = threadIdx.x >> 5;
  #pragma unroll
  for (int i = 0; i < 4; ++i) {
    int k = kt + ty + i * 8, n = nt + tx;
    t[ty + i * 8][tx] = (k < K && n < N) ? src[(size_t)k * srcStride + n] : 0.0f;
  }
  __syncthreads();
  #pragma unroll
  for (int i = 0; i < 4; ++i) {
    int n = nt + ty + i * 8, k = kt + tx;
    if (n < N && k < K) dst[(size_t)n * dstStride + k] = f2b(t[tx][ty + i * 8]);
  }
}

__global__ __launch_bounds__(256) void k_emb(const int* __restrict__ captions,
                                             const float* __restrict__ embedding,
                                             u16* __restrict__ embs) {
  int i = blockIdx.x * 256 + threadIdx.x;   // (T*B)*EMB, row m = t*64+b
  int m = i >> 9, k = i & 511;
  int t = m >> 6, b = m & 63;
  int cap = captions[b * T_ + t];
  embs[i] = f2b(embedding[(size_t)cap * EMB_ + k]);
}

__global__ __launch_bounds__(256) void k_bsum(const float* __restrict__ a,
                                              const float* __restrict__ b,
                                              float* __restrict__ o) {
  int i = blockIdx.x * 256 + threadIdx.x;   // 2048
  o[i] = a[i] + b[i];
}

__global__ __launch_bounds__(256) void k_catbias(const float* __restrict__ hb,
                                                 const float* __restrict__ cb,
                                                 float* __restrict__ o) {
  int i = blockIdx.x * 256 + threadIdx.x;   // 1024
  o[i] = (i < 512) ? hb[i] : cb[i - 512];
}

__global__ __launch_bounds__(256) void k_hc_pack(const float* __restrict__ initHC,
                                                 u16* __restrict__ h0_bf,
                                                 float* __restrict__ c_f) {
  int i = blockIdx.x * 256 + threadIdx.x;   // 64*512
  int b = i >> 9, d = i & 511;
  h0_bf[i] = f2b(initHC[b * 1024 + d]);
  c_f[i]  = initHC[b * 1024 + 512 + d];
}

// ---------------- small no-LDS MFMA GEMM (used once, M=64) ----------------
template <bool BF16OUT>
__global__ __launch_bounds__(256) void k_gemm_bt(
    const u16* __restrict__ Am, const u16* __restrict__ Bt,
    const float* __restrict__ bias, void* __restrict__ outp, int K, int N) {
  int m0 = blockIdx.x * 64, n0 = blockIdx.y * 64;
  int w = threadIdx.x >> 6, lane = threadIdx.x & 63;
  int lr = lane & 15, lg = lane >> 4;
  const u16* ap = Am + (size_t)(m0 + 16 * w + lr) * K + lg * 8;
  const u16* bp = Bt + (size_t)(n0 + lr) * K + lg * 8;
  f32x4 acc0 = {}, acc1 = {}, acc2 = {}, acc3 = {};
  for (int k = 0; k < K; k += 32) {
    bf16x8 a  = *reinterpret_cast<const bf16x8*>(ap + k);
    bf16x8 b0 = *reinterpret_cast<const bf16x8*>(bp + k);
    bf16x8 b1 = *reinterpret_cast<const bf16x8*>(bp + (size_t)16 * K + k);
    bf16x8 b2 = *reinterpret_cast<const bf16x8*>(bp + (size_t)32 * K + k);
    bf16x8 b3 = *reinterpret_cast<const bf16x8*>(bp + (size_t)48 * K + k);
    acc0 = mfma_bf16(a, b0, acc0);
    acc1 = mfma_bf16(a, b1, acc1);
    acc2 = mfma_bf16(a, b2, acc2);
    acc3 = mfma_bf16(a, b3, acc3);
  }
  int row = m0 + 16 * w + 4 * lg;
  f32x4 accs[4] = {acc0, acc1, acc2, acc3};
  #pragma unroll
  for (int ns = 0; ns < 4; ++ns) {
    int col = n0 + 16 * ns + lr;
    float bv = bias[col];
    #pragma unroll
    for (int r = 0; r < 4; ++r) {
      float v = accs[ns][r] + bv;
      if (BF16OUT) ((u16*)outp)[(size_t)(row + r) * N + col] = f2b(v);
      else         ((float*)outp)[(size_t)(row + r) * N + col] = v;
    }
  }
}

// ---------------- m97-style 128x128 LDS GEMM: out = A[M][K] @ Bt[N][K]^T + bias ----------------
template <bool BF16OUT>
__global__ __launch_bounds__(256) void k_gemm128(
    const u16* __restrict__ Am, const u16* __restrict__ Bt,
    const float* __restrict__ bias, void* __restrict__ outp, int K, int N) {
  __shared__ u16 lA[128 * 64];
  __shared__ u16 lB[128 * 64];
  int n0 = blockIdx.x * 128, m0 = blockIdx.y * 128;
  int w = threadIdx.x >> 6, lane = threadIdx.x & 63;
  int wr = w >> 1, wc = w & 1;
  int lr = lane & 15, lg = lane >> 4;
  int srow = lane >> 3;            // 0..7 within chunk
  int scol = (lane & 7) * 8;       // element col 0..56
  f32x4 acc[4][4] = {};
  for (int kt = 0; kt < K; kt += 64) {
    #pragma unroll
    for (int q = 0; q < 4; ++q) {
      int r = (w * 4 + q) * 8 + srow;   // tile row 0..127
      gl_lds16(Am + (size_t)(m0 + r) * K + kt + scol, &lA[(w * 4 + q) * 512]);
      gl_lds16(Bt + (size_t)(n0 + r) * K + kt + scol, &lB[(w * 4 + q) * 512]);
    }
    __syncthreads();
    #pragma unroll
    for (int kk = 0; kk < 2; ++kk) {
      bf16x8 af[4], bf[4];
      #pragma unroll
      for (int m = 0; m < 4; ++m)
        af[m] = *reinterpret_cast<const bf16x8*>(&lA[(wr * 64 + m * 16 + lr) * 64 + kk * 32 + lg * 8]);
      #pragma unroll
      for (int n = 0; n < 4; ++n)
        bf[n] = *reinterpret_cast<const bf16x8*>(&lB[(wc * 64 + n * 16 + lr) * 64 + kk * 32 + lg * 8]);
      #pragma unroll
      for (int m = 0; m < 4; ++m)
        #pragma unroll
        for (int n = 0; n < 4; ++n)
          acc[m][n] = mfma_bf16(af[m], bf[n], acc[m][n]);
    }
    __syncthreads();
  }
  #pragma unroll
  for (int n = 0; n < 4; ++n) {
    int col = n0 + wc * 64 + n * 16 + lr;
    float bv = bias[col];
    #pragma unroll
    for (int m = 0; m < 4; ++m) {
      int row = m0 + wr * 64 + m * 16 + lg * 4;
      #pragma unroll
      for (int r = 0; r < 4; ++r) {
        float v = acc[m][n][r] + bv;
        if (BF16OUT) ((u16*)outp)[(size_t)(row + r) * N + col] = f2b(v);
        else         ((float*)outp)[(size_t)(row + r) * N + col] = v;
      }
    }
  }
}

// ---- batched fc GEMM: preds[b][t][col] = Hall1[t*64+b][:] @ fcWT[col][:] + fc_b[col] ----
__global__ __launch_bounds__(256) void k_gemm_fc(
    const u16* __restrict__ Hall1, const u16* __restrict__ fcWT,
    const float* __restrict__ fc_b, float* __restrict__ preds_out) {
  __shared__ u16 lA[128 * 64];
  __shared__ u16 lB[128 * 64];
  int n0 = blockIdx.x * 128, m0 = blockIdx.y * 128;
  int w = threadIdx.x >> 6, lane = threadIdx.x & 63;
  int wr = w >> 1, wc = w & 1;
  int lr = lane & 15, lg = lane >> 4;
  int srow = lane >> 3;
  int scol = (lane & 7) * 8;
  f32x4 acc[4][4] = {};
  for (int kt = 0; kt < 512; kt += 64) {
    #pragma unroll
    for (int q = 0; q < 4; ++q) {
      int r = (w * 4 + q) * 8 + srow;
      gl_lds16(Hall1 + (size_t)(m0 + r) * 512 + kt + scol, &lA[(w * 4 + q) * 512]);
      gl_lds16(fcWT + (size_t)(n0 + r) * 512 + kt + scol, &lB[(w * 4 + q) * 512]);
    }
    __syncthreads();
    #pragma unroll
    for (int kk = 0; kk < 2; ++kk) {
      bf16x8 af[4], bf[4];
      #pragma unroll
      for (int m = 0; m < 4; ++m)
        af[m] = *reinterpret_cast<const bf16x8*>(&lA[(wr * 64 + m * 16 + lr) * 64 + kk * 32 + lg * 8]);
      #pragma unroll
      for (int n = 0; n < 4; ++n)
        bf[n] = *reinterpret_cast<const bf16x8*>(&lB[(wc * 64 + n * 16 + lr) * 64 + kk * 32 + lg * 8]);
      #pragma unroll
      for (int m = 0; m < 4; ++m)
        #pragma unroll
        for (int n = 0; n < 4; ++n)
          acc[m][n] = mfma_bf16(af[m], bf[n], acc[m][n]);
    }
    __syncthreads();
  }
  #pragma unroll
  for (int n = 0; n < 4; ++n) {
    int col = n0 + wc * 64 + n * 16 + lr;
    if (col >= V_) continue;
    float bv = fc_b[col];
    #pragma unroll
    for (int m = 0; m < 4; ++m) {
      int row = m0 + wr * 64 + m * 16 + lg * 4;
      #pragma unroll
      for (int r = 0; r < 4; ++r) {
        int rr = row + r;                 // = t*64 + b
        int t = rr >> 6, b = rr & 63;
        preds_out[((size_t)b * T_ + t) * V_ + col] = acc[m][n][r] + bv;
      }
    }
  }
}

// ---------------- persistent loop kernel (software grid barrier) ----------------
struct LoopArgs {
  const u16* catW;       // [NCAT][512]
  const u16* att1;       // [B*P][512] bf16
  const u16* enc;        // [B*P][E] bf16
  const u16* Wih2T;      // [2048][2048] bf16 (W_ih[512:]^T)
  const float* embW;     // [T][B][2048]  (emb@W_ih[:512] + b_ih + b_hh)
  u16* Hall;             // [T+1][B][D] bf16 (slice 0 = init h)
  float* c;              // [B][D]
  float* att2;           // [B][512]
  float* gate;           // [B][2048]
  float* gates;          // [B][2048]
  u16* gctx;             // [B][2048] bf16
  float* alphas;         // [B][T][P]
  const float* dec_b;
  const float* fbeta_b;
  const float* wf;       // full_att_W [512]
  const float* fab;      // full_att_b scalar
  unsigned* bar;         // grid barrier counter (zeroed each launch)
};

__global__ __launch_bounds__(256, 1) void k_loop(LoopArgs a) {
  __shared__ float sal[256];
  __shared__ float red[256];
  int blk = blockIdx.x, tid = threadIdx.x;
  int w = tid >> 6, lane = tid & 63;
  int lr = lane & 15, lg = lane >> 4;
  unsigned gen = 0;

  for (int t = 0; t < T_; ++t) {
    const u16* h = a.Hall + (size_t)t * B_ * D_;
    // ---- Phase A: fused h-GEMM over NCAT cols (blocks 0..71) ----
    if (blk < NCAT / 64) {
      int n0 = blk * 64;
      const u16* ap = h + (size_t)(16 * w + lr) * 512 + lg * 8;
      const u16* bp = a.catW + (size_t)(n0 + lr) * 512 + lg * 8;
      f32x4 acc0 = {}, acc1 = {}, acc2 = {}, acc3 = {};
      for (int k = 0; k < 512; k += 32) {
        bf16x8 av  = *reinterpret_cast<const bf16x8*>(ap + k);
        bf16x8 b0 = *reinterpret_cast<const bf16x8*>(bp + k);
        bf16x8 b1 = *reinterpret_cast<const bf16x8*>(bp + (size_t)16 * 512 + k);
        bf16x8 b2 = *reinterpret_cast<const bf16x8*>(bp + (size_t)32 * 512 + k);
        bf16x8 b3 = *reinterpret_cast<const bf16x8*>(bp + (size_t)48 * 512 + k);
        acc0 = mfma_bf16(av, b0, acc0);
        acc1 = mfma_bf16(av, b1, acc1);
        acc2 = mfma_bf16(av, b2, acc2);
        acc3 = mfma_bf16(av, b3, acc3);
      }
      int brow = 16 * w + 4 * lg;
      f32x4 accs[4] = {acc0, acc1, acc2, acc3};
      const float* embW_t = a.embW + (size_t)t * B_ * 2048;
      #pragma unroll
      for (int ns = 0; ns < 4; ++ns) {
        int n = n0 + 16 * ns + lr;
        #pragma unroll
        for (int r = 0; r < 4; ++r) {
          int b = brow + r;
          float v = accs[ns][r];
          if (n < 512) {
            a.att2[b * 512 + n] = v + a.dec_b[n];
          } else if (n < 2560) {
            int j = n - 512;
            a.gate[b * 2048 + j] = sigf(v + a.fbeta_b[j]);
          } else {
            int j = n - 2560;
            a.gates[b * 2048 + j] = v + embW_t[b * 2048 + j];
          }
        }
      }
    }
    gbar(a.bar, (++gen) * NBLK);

    // ---- Phase BD: per-b e + softmax + context (block = (b, quarter)) ----
    {
      int b = blk >> 2, q = blk & 3;
      float av[8], wvr[8];
      #pragma unroll
      for (int j = 0; j < 8; ++j) {
        av[j]  = a.att2[b * 512 + lane * 8 + j];
        wvr[j] = a.wf[lane * 8 + j];
      }
      float fb = a.fab[0];
      for (int p = w; p < P_; p += 4) {
        const u16* a1 = a.att1 + ((size_t)b * P_ + p) * 512 + lane * 8;
        float s = 0.f;
        #pragma unroll
        for (int j = 0; j < 8; ++j) {
          float x = b2f(a1[j]) + av[j];
          s += fmaxf(x, 0.f) * wvr[j];
        }
        #pragma unroll
        for (int off = 32; off > 0; off >>= 1) s += __shfl_xor(s, off);
        if (lane == 0) sal[p] = s + fb;
      }
      __syncthreads();
      float ev = (tid < P_) ? sal[tid] : -1e30f;
      red[tid] = ev; __syncthreads();
      for (int s2 = 128; s2 > 0; s2 >>= 1) {
        if (tid < s2) red[tid] = fmaxf(red[tid], red[tid + s2]);
        __syncthreads();
      }
      float mx = red[0]; __syncthreads();
      float ex = (tid < P_) ? __expf(ev - mx) : 0.f;
      red[tid] = ex; __syncthreads();
      for (int s2 = 128; s2 > 0; s2 >>= 1) {
        if (tid < s2) red[tid] += red[tid + s2];
        __syncthreads();
      }
      float inv = 1.0f / red[0];
      __syncthreads();
      if (tid < P_) {
        float al = ex * inv;
        sal[tid] = al;
        if (q == 0) a.alphas[((size_t)b * T_ + t) * P_ + tid] = al;
      }
      __syncthreads();
      int col = q * 512 + tid;
      const u16* ep = a.enc + (size_t)b * P_ * E_ + col;
      float ac0 = 0.f, ac1 = 0.f;
      #pragma unroll 4
      for (int p = 0; p < P_; ++p) {
        float al = sal[p];
        ac0 += al * b2f(ep[(size_t)p * E_]);
        ac1 += al * b2f(ep[(size_t)p * E_ + 256]);
      }
      a.gctx[b * E_ + col]       = f2b(ac0 * a.gate[b * E_ + col]);
      a.gctx[b * E_ + col + 256] = f2b(ac1 * a.gate[b * E_ + col + 256]);
    }
    gbar(a.bar, (++gen) * NBLK);

    // ---- Phase E1: gates += gctx @ Wih2T (split-K8, atomics) ----
    {
      int n0 = (blk & 31) * 64;
      int k0 = (blk >> 5) * 256;
      const u16* ap = a.gctx + (size_t)(16 * w + lr) * 2048 + lg * 8 + k0;
      const u16* bp = a.Wih2T + (size_t)(n0 + lr) * 2048 + lg * 8 + k0;
      f32x4 acc0 = {}, acc1 = {}, acc2 = {}, acc3 = {};
      for (int k = 0; k < 256; k += 32) {
        bf16x8 av  = *reinterpret_cast<const bf16x8*>(ap + k);
        bf16x8 b0 = *reinterpret_cast<const bf16x8*>(bp + k);
        bf16x8 b1 = *reinterpret_cast<const bf16x8*>(bp + (size_t)16 * 2048 + k);
        bf16x8 b2 = *reinterpret_cast<const bf16x8*>(bp + (size_t)32 * 2048 + k);
        bf16x8 b3 = *reinterpret_cast<const bf16x8*>(bp + (size_t)48 * 2048 + k);
        acc0 = mfma_bf16(av, b0, acc0);
        acc1 = mfma_bf16(av, b1, acc1);
        acc2 = mfma_bf16(av, b2, acc2);
        acc3 = mfma_bf16(av, b3, acc3);
      }
      int brow = 16 * w + 4 * lg;
      f32x4 accs[4] = {acc0, acc1, acc2, acc3};
      #pragma unroll
      for (int ns = 0; ns < 4; ++ns) {
        int n = n0 + 16 * ns + lr;
        #pragma unroll
        for (int r = 0; r < 4; ++r)
          atomicAdd(&a.gates[(brow + r) * 2048 + n], accs[ns][r]);
      }
    }
    gbar(a.bar, (++gen) * NBLK);

    // ---- Phase E2: LSTM cell (blocks 0..127) ----
    if (blk < 128) {
      int i = blk * 256 + tid;
      int b = i >> 9, d = i & 511;
      const float* g = a.gates + (size_t)b * 2048;
      float gi = g[d], gf = g[d + 512], gg = g[d + 1024], go = g[d + 1536];
      float cn = sigf(gf) * a.c[i] + sigf(gi) * tanhf(gg);
      float hn = sigf(go) * tanhf(cn);
      a.c[i] = cn;
      a.Hall[(size_t)(t + 1) * B_ * D_ + i] = f2b(hn);
    }
    gbar(a.bar, (++gen) * NBLK);
  }
}

// ---------------- host ----------------
extern "C" void kernel_launch(void* const* d_in, const int* in_sizes, int n_in,
                              void* d_out, int out_size, void* d_ws, size_t ws_size,
                              hipStream_t stream) {
  (void)in_sizes; (void)n_in; (void)out_size;
  const float* enc        = (const float*)d_in[0];
  const int*   captions   = (const int*)d_in[1];
  const float* enc_att_W  = (const float*)d_in[3];
  const float* enc_att_b  = (const float*)d_in[4];
  const float* dec_att_W  = (const float*)d_in[5];
  const float* dec_att_b  = (const float*)d_in[6];
  const float* full_att_W = (const float*)d_in[7];
  const float* full_att_b = (const float*)d_in[8];
  const float* embedding  = (const float*)d_in[9];
  const float* W_ih       = (const float*)d_in[10];
  const float* b_ih       = (const float*)d_in[11];
  const float* W_hh       = (const float*)d_in[12];
  const float* b_hh       = (const float*)d_in[13];
  const float* init_h_W   = (const float*)d_in[14];
  const float* init_h_b   = (const float*)d_in[15];
  const float* init_c_W   = (const float*)d_in[16];
  const float* init_c_b   = (const float*)d_in[17];
  const float* fc_W       = (const float*)d_in[18];
  const float* fc_b       = (const float*)d_in[19];
  const float* f_beta_W   = (const float*)d_in[20];
  const float* f_beta_b   = (const float*)d_in[21];

  float* preds_out  = (float*)d_out;                          // [64][40][10000]
  float* alphas_out = (float*)d_out + (size_t)B_ * T_ * V_;   // [64][40][196]

  char* w = (char*)d_ws;
  auto alloc = [&](size_t bytes) -> char* {
    char* p = w; w += (bytes + 255) & ~(size_t)255; return p;
  };
  u16*   enc_bf   = (u16*)  alloc((size_t)B_ * P_ * E_ * 2);       // 51.4 MB
  u16*   att1_bf  = (u16*)  alloc((size_t)B_ * P_ * A_ * 2);       // 12.8 MB
  u16*   catW     = (u16*)  alloc((size_t)NCAT * 512 * 2);         //  4.7 MB
  u16*   fcWT     = (u16*)  alloc((size_t)VPAD * 512 * 2);         // 10.4 MB
  u16*   encattWT = (u16*)  alloc((size_t)A_ * E_ * 2);            //  2.1 MB
  u16*   WihembT  = (u16*)  alloc((size_t)2048 * 512 * 2);         //  2.1 MB
  u16*   Wih2T    = (u16*)  alloc((size_t)2048 * 2048 * 2);        //  8.4 MB
  u16*   embs_bf  = (u16*)  alloc((size_t)T_ * B_ * EMB_ * 2);     //  2.6 MB
  float* embW     = (float*)alloc((size_t)T_ * B_ * 2048 * 4);     // 21.0 MB
  u16*   Hall     = (u16*)  alloc((size_t)(T_ + 1) * B_ * D_ * 2); //  2.7 MB
  u16*   catInit  = (u16*)  alloc((size_t)1024 * 2048 * 2);        //  4.2 MB
  float* catInitB = (float*)alloc(1024 * 4);
  float* initHC   = (float*)alloc((size_t)B_ * 1024 * 4);
  u16*   meanE_bf = (u16*)  alloc((size_t)B_ * E_ * 2);
  float* c_f      = (float*)alloc((size_t)B_ * D_ * 4);
  float* att2_f   = (float*)alloc((size_t)B_ * A_ * 4);
  float* gate_f   = (float*)alloc((size_t)B_ * E_ * 4);
  float* gates_f  = (float*)alloc((size_t)B_ * 2048 * 4);
  u16*   gctx_bf  = (u16*)  alloc((size_t)B_ * E_ * 2);
  float* bsum     = (float*)alloc(2048 * 4);
  unsigned* bar   = (unsigned*)alloc(256);
  if ((size_t)(w - (char*)d_ws) > ws_size) return;  // ws too small -> visible as absmax fail

  // ---- prolog ----
  hipMemsetAsync(bar, 0, 4, stream);
  k_cvt_bf16<<<25088, 256, 0, stream>>>(enc, enc_bf, (B_ * P_ * E_) / 4);
  k_mean<<<512, 256, 0, stream>>>(enc, meanE_bf);
  k_transpose_bf16<<<dim3(16, 16), 256, 0, stream>>>(dec_att_W, 512, catW, 512, 512, 512);
  k_transpose_bf16<<<dim3(16, 64), 256, 0, stream>>>(f_beta_W, 2048, catW + (size_t)512 * 512, 512, 2048, 512);
  k_transpose_bf16<<<dim3(16, 64), 256, 0, stream>>>(W_hh, 2048, catW + (size_t)2560 * 512, 512, 2048, 512);
  hipMemsetAsync(fcWT + (size_t)V_ * 512, 0, (size_t)(VPAD - V_) * 512 * 2, stream);
  k_transpose_bf16<<<dim3(16, 313), 256, 0, stream>>>(fc_W, 10000, fcWT, 512, 10000, 512);
  k_transpose_bf16<<<dim3(64, 16), 256, 0, stream>>>(enc_att_W, 512, encattWT, 2048, 512, 2048);
  k_transpose_bf16<<<dim3(16, 64), 256, 0, stream>>>(W_ih, 2048, WihembT, 512, 2048, 512);
  k_transpose_bf16<<<dim3(64, 64), 256, 0, stream>>>(W_ih + (size_t)512 * 2048, 2048, Wih2T, 2048, 2048, 2048);
  k_transpose_bf16<<<dim3(64, 16), 256, 0, stream>>>(init_h_W, 512, catInit, 2048, 512, 2048);
  k_transpose_bf16<<<dim3(64, 16), 256, 0, stream>>>(init_c_W, 512, catInit + (size_t)512 * 2048, 2048, 512, 2048);
  k_catbias<<<4, 256, 0, stream>>>(init_h_b, init_c_b, catInitB);
  k_bsum<<<8, 256, 0, stream>>>(b_ih, b_hh, bsum);
  k_emb<<<5120, 256, 0, stream>>>(captions, embedding, embs_bf);
  k_gemm_bt<false><<<dim3(1, 16), 256, 0, stream>>>(meanE_bf, catInit, catInitB, initHC, 2048, 1024);
  k_hc_pack<<<128, 256, 0, stream>>>(initHC, Hall, c_f);
  k_gemm128<true><<<dim3(4, 98), 256, 0, stream>>>(enc_bf, encattWT, enc_att_b, att1_bf, 2048, 512);
  k_gemm128<false><<<dim3(16, 20), 256, 0, stream>>>(embs_bf, WihembT, bsum, embW, 512, 2048);

  // ---- persistent loop (software grid barrier; grid == CU count) ----
  LoopArgs la;
  la.catW = catW; la.att1 = att1_bf; la.enc = enc_bf; la.Wih2T = Wih2T;
  la.embW = embW; la.Hall = Hall; la.c = c_f; la.att2 = att2_f;
  la.gate = gate_f; la.gates = gates_f; la.gctx = gctx_bf; la.alphas = alphas_out;
  la.dec_b = dec_att_b; la.fbeta_b = f_beta_b; la.wf = full_att_W; la.fab = full_att_b;
  la.bar = bar;
  k_loop<<<NBLK, 256, 0, stream>>>(la);

  // ---- batched fc: preds for all t ----
  k_gemm_fc<<<dim3(VPAD / 128, (T_ * B_) / 128), 256, 0, stream>>>(
      Hall + (size_t)B_ * D_, fcWT, fc_b, preds_out);
}